// Round 1
// baseline (139.751 us; speedup 1.0000x reference)
//
#include <hip/hip_runtime.h>

// KnowledgeGraphEmbedding: out[4][P]
//   dist[p] = || Lp_w[p] @ wi - Rp_w[p] @ wj ||^2
//   out = { dist*is_edge, dist*is_not, is_edge, is_not }
//
// Memory-bound: 2 * P*H*E*4B = 737 MB streamed once. Target ~117 us @ 6.3 TB/s.

#define KGE_P 1024
#define KGE_H 300
#define KGE_E 300
#define KGE_E4 75   // E / 4 floats per float4 row

__global__ __launch_bounds__(256) void kge_kernel(
    const float* __restrict__ tag_rep,
    const float* __restrict__ Lp_w,
    const float* __restrict__ Rp_w,
    const int*   __restrict__ relation,
    const int*   __restrict__ tag1_idx,
    const int*   __restrict__ tag2_idx,
    float*       __restrict__ out)
{
    __shared__ float s_wi[KGE_E];
    __shared__ float s_wj[KGE_E];
    __shared__ float s_wave[4];

    const int p    = blockIdx.x;
    const int tid  = threadIdx.x;
    const int lane = tid & 63;
    const int wave = tid >> 6;

    // Stage the two tag-embedding rows into LDS.
    {
        const int t1 = tag1_idx[0];
        const int t2 = tag2_idx[0];
        const float* wi = tag_rep + (size_t)t1 * KGE_E;
        const float* wj = tag_rep + (size_t)t2 * KGE_E;
        for (int i = tid; i < KGE_E; i += 256) {
            s_wi[i] = wi[i];
            s_wj[i] = wj[i];
        }
    }
    __syncthreads();

    const float4* __restrict__ Lbase = (const float4*)(Lp_w + (size_t)p * KGE_H * KGE_E);
    const float4* __restrict__ Rbase = (const float4*)(Rp_w + (size_t)p * KGE_H * KGE_E);
    const float4* s_wi4 = (const float4*)s_wi;
    const float4* s_wj4 = (const float4*)s_wj;

    float dist_acc = 0.0f;

    // Each wave handles rows h = wave, wave+4, ... (75 rows per wave).
    for (int h = wave; h < KGE_H; h += 4) {
        const float4* __restrict__ Lr = Lbase + h * KGE_E4;
        const float4* __restrict__ Rr = Rbase + h * KGE_E4;

        float partial = 0.0f;
        // 75 float4 per row over 64 lanes: iter 0 all lanes, iter 1 lanes 0..10.
        for (int i = lane; i < KGE_E4; i += 64) {
            float4 lv = Lr[i];
            float4 rv = Rr[i];
            float4 a  = s_wi4[i];
            float4 b  = s_wj4[i];
            partial += lv.x * a.x + lv.y * a.y + lv.z * a.z + lv.w * a.w;
            partial -= rv.x * b.x + rv.y * b.y + rv.z * b.z + rv.w * b.w;
        }
        // Wave-64 butterfly reduce -> every lane holds the full row diff.
        #pragma unroll
        for (int off = 32; off >= 1; off >>= 1)
            partial += __shfl_xor(partial, off, 64);

        dist_acc += partial * partial;  // identical in all lanes
    }

    if (lane == 0) s_wave[wave] = dist_acc;
    __syncthreads();

    if (tid == 0) {
        const float dist = s_wave[0] + s_wave[1] + s_wave[2] + s_wave[3];
        const int rel = relation[p];
        const float is_edge = (rel == 1) ? 1.0f : 0.0f;
        const float is_not  = (rel == 0) ? 1.0f : 0.0f;
        out[0 * KGE_P + p] = dist * is_edge;
        out[1 * KGE_P + p] = dist * is_not;
        out[2 * KGE_P + p] = is_edge;
        out[3 * KGE_P + p] = is_not;
    }
}

extern "C" void kernel_launch(void* const* d_in, const int* in_sizes, int n_in,
                              void* d_out, int out_size, void* d_ws, size_t ws_size,
                              hipStream_t stream) {
    const float* tag_rep  = (const float*)d_in[0];
    const float* Lp_w     = (const float*)d_in[1];
    const float* Rp_w     = (const float*)d_in[2];
    const int*   relation = (const int*)d_in[3];
    const int*   tag1_idx = (const int*)d_in[4];
    const int*   tag2_idx = (const int*)d_in[5];
    float*       out      = (float*)d_out;

    kge_kernel<<<KGE_P, 256, 0, stream>>>(tag_rep, Lp_w, Rp_w,
                                          relation, tag1_idx, tag2_idx, out);
}